// Round 1
// baseline (271.771 us; speedup 1.0000x reference)
//
#include <hip/hip_runtime.h>
#include <math.h>

#define BATCH 64
#define HIMG 224
#define WIMG 224
#define IMGPLANE (HIMG*WIMG)   // 50176
#define CF 512
#define HF 28
#define WF 28
#define POS (HF*WF)            // 784
#define ALPHA_C 0.15f
#define EPS_C 1e-6f

// ---- ws layout (in floats) ----
#define OFF_VAR 0
#define VAR_CNT (BATCH*IMGPLANE)            // 3,211,264
#define OFF_MM  (OFF_VAR + VAR_CNT)         // 2*BATCH uints: [min,max] per sample (nonneg-float-as-uint)
#define OFF_SAL (OFF_MM + 2*BATCH)          // BATCH*POS
#define OFF_AP  (OFF_SAL + BATCH*POS)       // 2*BATCH*POS partial channel sums
#define OFF_ACC (OFF_AP + 2*BATCH*POS)      // 1 float loss accumulator

__global__ void init_k(float* ws) {
    int t = threadIdx.x;
    unsigned* mm = (unsigned*)(ws + OFF_MM);
    if (t < BATCH) { mm[2*t] = 0x7F800000u; mm[2*t+1] = 0u; }  // +inf / 0.0
    if (t == 0) ws[OFF_ACC] = 0.0f;
}

// ---- gray -> 5x5 box var (zero-padded SAME), per-sample min/max ----
#define TILE 32
#define HALO 2
#define STW 36
__global__ __launch_bounds__(256) void var_k(const float* __restrict__ img,
                                             float* __restrict__ ws) {
    __shared__ float g[STW][STW + 1];
    __shared__ float rmn[256], rmx[256];
    int b = blockIdx.z;
    int tx0 = blockIdx.x * TILE, ty0 = blockIdx.y * TILE;
    int tid = threadIdx.x;
    const float* imb = img + (size_t)b * 3 * IMGPLANE;

    for (int i = tid; i < STW * STW; i += 256) {
        int sy = i / STW, sx = i - sy * STW;
        int gy = ty0 - HALO + sy, gx = tx0 - HALO + sx;
        float v = 0.0f;
        if ((unsigned)gy < HIMG && (unsigned)gx < WIMG) {
            int o = gy * WIMG + gx;
            v = 0.299f * imb[o] + 0.587f * imb[IMGPLANE + o] + 0.114f * imb[2 * IMGPLANE + o];
        }
        g[sy][sx] = v;
    }
    __syncthreads();

    float* var = ws + OFF_VAR + (size_t)b * IMGPLANE;
    float vmin = INFINITY, vmax = 0.0f;
    int lx = tid & 31, lyb = tid >> 5;  // 32 x 8 threads
    for (int k = 0; k < 4; k++) {
        int ly = lyb + 8 * k;
        float s = 0.0f, s2 = 0.0f;
        #pragma unroll
        for (int dy = 0; dy < 5; dy++)
            #pragma unroll
            for (int dx = 0; dx < 5; dx++) {
                float u = g[ly + dy][lx + dx];
                s += u; s2 += u * u;
            }
        float m = s * 0.04f, m2 = s2 * 0.04f;
        float v = fmaxf(m2 - m * m, 0.0f);
        var[(ty0 + ly) * WIMG + (tx0 + lx)] = v;
        vmin = fminf(vmin, v); vmax = fmaxf(vmax, v);
    }
    rmn[tid] = vmin; rmx[tid] = vmax;
    __syncthreads();
    for (int s = 128; s > 0; s >>= 1) {
        if (tid < s) {
            rmn[tid] = fminf(rmn[tid], rmn[tid + s]);
            rmx[tid] = fmaxf(rmx[tid], rmx[tid + s]);
        }
        __syncthreads();
    }
    if (tid == 0) {
        unsigned* mm = (unsigned*)(ws + OFF_MM);
        atomicMin(&mm[2*b],     __float_as_uint(rmn[0]));  // var >= 0: uint order == float order
        atomicMax(&mm[2*b + 1], __float_as_uint(rmx[0]));
    }
}

// ---- separable 16-tap triangle (antialiased bilinear) resize 224->28, then normalize ----
__global__ __launch_bounds__(256) void resize_k(float* __restrict__ ws) {
    __shared__ float hres[HIMG][WF + 1];   // 224 x 29 floats = 25,984 B
    int b = blockIdx.x;
    int tid = threadIdx.x;
    const float* var = ws + OFF_VAR + (size_t)b * IMGPLANE;

    // horizontal: 224 rows x 28 cols
    for (int idx = tid; idx < HIMG * WF; idx += 256) {
        int y = idx / WF, i = idx - y * WF;
        float acc = 0.0f, wsum = 0.0f;
        int j0 = 8 * i - 4;
        #pragma unroll
        for (int t = 0; t < 16; t++) {
            int j = j0 + t;
            float w = 8.0f - fabsf((float)t - 7.5f);
            if ((unsigned)j < WIMG) { acc += w * var[y * WIMG + j]; wsum += w; }
        }
        hres[y][i] = acc / wsum;
    }
    __syncthreads();

    const unsigned* mm = (const unsigned*)(ws + OFF_MM);
    float mn = __uint_as_float(mm[2*b]);
    float mx = __uint_as_float(mm[2*b + 1]);
    float denom = mx - mn;
    bool ok = denom > EPS_C;
    float* sal = ws + OFF_SAL + b * POS;

    // vertical: 28 x 28
    for (int idx = tid; idx < POS; idx += 256) {
        int yo = idx / WF, x = idx - yo * WF;
        float acc = 0.0f, wsum = 0.0f;
        int j0 = 8 * yo - 4;
        #pragma unroll
        for (int t = 0; t < 16; t++) {
            int j = j0 + t;
            float w = 8.0f - fabsf((float)t - 7.5f);
            if ((unsigned)j < HIMG) { acc += w * hres[j][x]; wsum += w; }
        }
        float sraw = acc / wsum;
        sal[idx] = ok ? (sraw - mn) / denom : 0.5f;
    }
}

// ---- sum of squares over channels, split in two halves for occupancy ----
__global__ __launch_bounds__(256) void attn_k(const float* __restrict__ f,
                                              float* __restrict__ ws) {
    int p = blockIdx.x * 256 + threadIdx.x;
    int b = blockIdx.y, z = blockIdx.z;
    if (p >= POS) return;
    const float* fp = f + ((size_t)b * CF + (size_t)z * 256) * POS + p;
    float acc = 0.0f;
    #pragma unroll 16
    for (int c = 0; c < 256; c++) {
        float v = fp[(size_t)c * POS];
        acc += v * v;
    }
    ws[OFF_AP + ((size_t)z * BATCH + b) * POS + p] = acc;
}

// ---- per-sample: attn = sqrt(mean), min/max, normalized MSE vs sal ----
__global__ __launch_bounds__(256) void loss_k(float* __restrict__ ws) {
    __shared__ float attn[POS];
    __shared__ float red[256];
    int b = blockIdx.x, tid = threadIdx.x;
    const float* a0 = ws + OFF_AP + (size_t)b * POS;
    const float* a1 = ws + OFF_AP + ((size_t)BATCH + b) * POS;

    float mn = INFINITY, mx = -INFINITY;
    for (int p = tid; p < POS; p += 256) {
        float a = sqrtf((a0[p] + a1[p]) * (1.0f / CF));
        attn[p] = a;
        mn = fminf(mn, a); mx = fmaxf(mx, a);
    }
    red[tid] = mn; __syncthreads();
    for (int s = 128; s > 0; s >>= 1) {
        if (tid < s) red[tid] = fminf(red[tid], red[tid + s]);
        __syncthreads();
    }
    mn = red[0]; __syncthreads();
    red[tid] = mx; __syncthreads();
    for (int s = 128; s > 0; s >>= 1) {
        if (tid < s) red[tid] = fmaxf(red[tid], red[tid + s]);
        __syncthreads();
    }
    mx = red[0]; __syncthreads();

    float denom = mx - mn;
    bool ok = denom > EPS_C;
    const float* sal = ws + OFF_SAL + b * POS;
    float lsum = 0.0f;
    for (int p = tid; p < POS; p += 256) {
        float an = ok ? (attn[p] - mn) / denom : 0.5f;
        float d = an - sal[p];
        lsum += d * d;
    }
    red[tid] = lsum; __syncthreads();
    for (int s = 128; s > 0; s >>= 1) {
        if (tid < s) red[tid] += red[tid + s];
        __syncthreads();
    }
    if (tid == 0)
        atomicAdd(ws + OFF_ACC, red[0] * (ALPHA_C / (float)(BATCH * POS)));
}

__global__ void final_k(const float* __restrict__ ws, float* __restrict__ out) {
    if (threadIdx.x == 0) out[0] = ws[OFF_ACC];
}

extern "C" void kernel_launch(void* const* d_in, const int* in_sizes, int n_in,
                              void* d_out, int out_size, void* d_ws, size_t ws_size,
                              hipStream_t stream) {
    const float* features = (const float*)d_in[0];  // [64,512,28,28]
    const float* images   = (const float*)d_in[1];  // [64,3,224,224]
    float* ws  = (float*)d_ws;
    float* out = (float*)d_out;

    hipLaunchKernelGGL(init_k,   dim3(1),           dim3(256), 0, stream, ws);
    hipLaunchKernelGGL(var_k,    dim3(7, 7, BATCH), dim3(256), 0, stream, images, ws);
    hipLaunchKernelGGL(resize_k, dim3(BATCH),       dim3(256), 0, stream, ws);
    hipLaunchKernelGGL(attn_k,   dim3(4, BATCH, 2), dim3(256), 0, stream, features, ws);
    hipLaunchKernelGGL(loss_k,   dim3(BATCH),       dim3(256), 0, stream, ws);
    hipLaunchKernelGGL(final_k,  dim3(1),           dim3(64),  0, stream, ws, out);
}

// Round 2
// 252.331 us; speedup vs baseline: 1.0770x; 1.0770x over previous
//
#include <hip/hip_runtime.h>
#include <math.h>

#define BATCH 64
#define HIMG 224
#define WIMG 224
#define IMGPLANE (HIMG*WIMG)   // 50176
#define CF 512
#define HF 28
#define WF 28
#define POS (HF*WF)            // 784
#define ALPHA_C 0.15f
#define EPS_C 1e-6f
#define NBLK 49                // var blocks per sample (7x7)

// ---- ws layout (in floats) ----
#define OFF_VAR 0
#define VAR_CNT (BATCH*IMGPLANE)             // 3,211,264
#define OFF_BMM (OFF_VAR + VAR_CNT)          // BATCH*NBLK*2 per-block [min,max]
#define OFF_AP  (OFF_BMM + BATCH*NBLK*2)     // 2*BATCH*POS partial channel sums
#define OFF_LP  (OFF_AP + 2*BATCH*POS)       // BATCH per-sample loss partials

// ---- gray -> 5x5 box var (zero-padded SAME), per-block min/max partials ----
#define TILE 32
#define HALO 2
#define STW 36
__global__ __launch_bounds__(256) void var_k(const float* __restrict__ img,
                                             float* __restrict__ ws) {
    __shared__ float g[STW][STW + 1];
    __shared__ float wmn[4], wmx[4];
    int b = blockIdx.z;
    int tx0 = blockIdx.x * TILE, ty0 = blockIdx.y * TILE;
    int tid = threadIdx.x;
    const float* imb = img + (size_t)b * 3 * IMGPLANE;

    for (int i = tid; i < STW * STW; i += 256) {
        int sy = i / STW, sx = i - sy * STW;
        int gy = ty0 - HALO + sy, gx = tx0 - HALO + sx;
        float v = 0.0f;
        if ((unsigned)gy < HIMG && (unsigned)gx < WIMG) {
            int o = gy * WIMG + gx;
            v = 0.299f * imb[o] + 0.587f * imb[IMGPLANE + o] + 0.114f * imb[2 * IMGPLANE + o];
        }
        g[sy][sx] = v;
    }
    __syncthreads();

    float* var = ws + OFF_VAR + (size_t)b * IMGPLANE;
    float vmin = INFINITY, vmax = 0.0f;
    int lx = tid & 31, lyb = tid >> 5;  // 32 x 8 threads
    for (int k = 0; k < 4; k++) {
        int ly = lyb + 8 * k;
        float s = 0.0f, s2 = 0.0f;
        #pragma unroll
        for (int dy = 0; dy < 5; dy++)
            #pragma unroll
            for (int dx = 0; dx < 5; dx++) {
                float u = g[ly + dy][lx + dx];
                s += u; s2 += u * u;
            }
        float m = s * 0.04f, m2 = s2 * 0.04f;
        float v = fmaxf(m2 - m * m, 0.0f);
        var[(ty0 + ly) * WIMG + (tx0 + lx)] = v;
        vmin = fminf(vmin, v); vmax = fmaxf(vmax, v);
    }
    // wave reduce (64 lanes), then 4 waves -> thread 0
    #pragma unroll
    for (int o = 32; o > 0; o >>= 1) {
        vmin = fminf(vmin, __shfl_xor(vmin, o));
        vmax = fmaxf(vmax, __shfl_xor(vmax, o));
    }
    int w = tid >> 6;
    if ((tid & 63) == 0) { wmn[w] = vmin; wmx[w] = vmax; }
    __syncthreads();
    if (tid == 0) {
        float mn = fminf(fminf(wmn[0], wmn[1]), fminf(wmn[2], wmn[3]));
        float mx = fmaxf(fmaxf(wmx[0], wmx[1]), fmaxf(wmx[2], wmx[3]));
        int blk = b * NBLK + blockIdx.y * 7 + blockIdx.x;
        ws[OFF_BMM + 2 * blk]     = mn;
        ws[OFF_BMM + 2 * blk + 1] = mx;
    }
}

// ---- sum of squares over channels, split in two halves for occupancy ----
__global__ __launch_bounds__(256) void attn_k(const float* __restrict__ f,
                                              float* __restrict__ ws) {
    int p = blockIdx.x * 256 + threadIdx.x;
    int b = blockIdx.y, z = blockIdx.z;
    if (p >= POS) return;
    const float* fp = f + ((size_t)b * CF + (size_t)z * 256) * POS + p;
    float acc = 0.0f;
    #pragma unroll 16
    for (int c = 0; c < 256; c++) {
        float v = fp[(size_t)c * POS];
        acc += v * v;
    }
    ws[OFF_AP + ((size_t)z * BATCH + b) * POS + p] = acc;
}

// ---- per sample: minmax reduce, 16-tap separable resize, attn norm, MSE ----
__global__ __launch_bounds__(256) void fused_k(float* __restrict__ ws) {
    __shared__ float hres[HIMG][WF + 1];   // 25,984 B
    __shared__ float wred[4];
    __shared__ float s_mn, s_mx;
    int b = blockIdx.x;
    int tid = threadIdx.x;

    // 1) reduce 49 per-block var min/max pairs (first wave only)
    if (tid < 64) {
        float mn = INFINITY, mx = 0.0f;
        if (tid < NBLK) {
            mn = ws[OFF_BMM + 2 * (b * NBLK + tid)];
            mx = ws[OFF_BMM + 2 * (b * NBLK + tid) + 1];
        }
        #pragma unroll
        for (int o = 32; o > 0; o >>= 1) {
            mn = fminf(mn, __shfl_xor(mn, o));
            mx = fmaxf(mx, __shfl_xor(mx, o));
        }
        if (tid == 0) { s_mn = mn; s_mx = mx; }
    }

    // 2) horizontal resize: 224 rows x 28 cols
    const float* var = ws + OFF_VAR + (size_t)b * IMGPLANE;
    for (int idx = tid; idx < HIMG * WF; idx += 256) {
        int y = idx / WF, i = idx - y * WF;
        float acc = 0.0f, wsum = 0.0f;
        int j0 = 8 * i - 4;
        #pragma unroll
        for (int t = 0; t < 16; t++) {
            int j = j0 + t;
            float w = 8.0f - fabsf((float)t - 7.5f);
            if ((unsigned)j < WIMG) { acc += w * var[y * WIMG + j]; wsum += w; }
        }
        hres[y][i] = acc / wsum;
    }
    __syncthreads();

    float vmn = s_mn, vmx = s_mx;
    float vden = vmx - vmn;
    bool vok = vden > EPS_C;

    // 3) vertical resize -> sal (registers); attn partial read -> attn (registers)
    const float* a0 = ws + OFF_AP + (size_t)b * POS;
    const float* a1 = ws + OFF_AP + ((size_t)BATCH + b) * POS;
    float salv[4], attnv[4];
    float amn = INFINITY, amx = -INFINITY;
    #pragma unroll
    for (int k = 0; k < 4; k++) {
        int idx = tid + 256 * k;
        salv[k] = 0.0f; attnv[k] = 0.0f;
        if (idx < POS) {
            int yo = idx / WF, x = idx - yo * WF;
            float acc = 0.0f, wsum = 0.0f;
            int j0 = 8 * yo - 4;
            #pragma unroll
            for (int t = 0; t < 16; t++) {
                int j = j0 + t;
                float w = 8.0f - fabsf((float)t - 7.5f);
                if ((unsigned)j < HIMG) { acc += w * hres[j][x]; wsum += w; }
            }
            float sraw = acc / wsum;
            salv[k] = vok ? (sraw - vmn) / vden : 0.5f;
            float a = sqrtf((a0[idx] + a1[idx]) * (1.0f / CF));
            attnv[k] = a;
            amn = fminf(amn, a); amx = fmaxf(amx, a);
        }
    }

    // 4) block min/max of attn
    #pragma unroll
    for (int o = 32; o > 0; o >>= 1) {
        amn = fminf(amn, __shfl_xor(amn, o));
        amx = fmaxf(amx, __shfl_xor(amx, o));
    }
    int w = tid >> 6;
    if ((tid & 63) == 0) wred[w] = amn;
    __syncthreads();
    if (tid < 64) {
        float m = fminf(fminf(wred[0], wred[1]), fminf(wred[2], wred[3]));
        if (tid == 0) s_mn = m;
    }
    __syncthreads();
    if ((tid & 63) == 0) wred[w] = amx;
    __syncthreads();
    if (tid < 64) {
        float m = fmaxf(fmaxf(wred[0], wred[1]), fmaxf(wred[2], wred[3]));
        if (tid == 0) s_mx = m;
    }
    __syncthreads();
    amn = s_mn; amx = s_mx;
    float aden = amx - amn;
    bool aok = aden > EPS_C;

    // 5) MSE partial
    float lsum = 0.0f;
    #pragma unroll
    for (int k = 0; k < 4; k++) {
        int idx = tid + 256 * k;
        if (idx < POS) {
            float an = aok ? (attnv[k] - amn) / aden : 0.5f;
            float d = an - salv[k];
            lsum += d * d;
        }
    }
    #pragma unroll
    for (int o = 32; o > 0; o >>= 1) lsum += __shfl_xor(lsum, o);
    if ((tid & 63) == 0) wred[w] = lsum;
    __syncthreads();
    if (tid == 0)
        ws[OFF_LP + b] = wred[0] + wred[1] + wred[2] + wred[3];
}

__global__ void final_k(const float* __restrict__ ws, float* __restrict__ out) {
    int t = threadIdx.x;
    float v = ws[OFF_LP + t];   // 64 threads, one wave
    #pragma unroll
    for (int o = 32; o > 0; o >>= 1) v += __shfl_xor(v, o);
    if (t == 0) out[0] = v * (ALPHA_C / (float)(BATCH * POS));
}

extern "C" void kernel_launch(void* const* d_in, const int* in_sizes, int n_in,
                              void* d_out, int out_size, void* d_ws, size_t ws_size,
                              hipStream_t stream) {
    const float* features = (const float*)d_in[0];  // [64,512,28,28]
    const float* images   = (const float*)d_in[1];  // [64,3,224,224]
    float* ws  = (float*)d_ws;
    float* out = (float*)d_out;

    hipLaunchKernelGGL(var_k,   dim3(7, 7, BATCH), dim3(256), 0, stream, images, ws);
    hipLaunchKernelGGL(attn_k,  dim3(4, BATCH, 2), dim3(256), 0, stream, features, ws);
    hipLaunchKernelGGL(fused_k, dim3(BATCH),       dim3(256), 0, stream, ws);
    hipLaunchKernelGGL(final_k, dim3(1),           dim3(64),  0, stream, ws, out);
}

// Round 3
// 196.241 us; speedup vs baseline: 1.3849x; 1.2858x over previous
//
#include <hip/hip_runtime.h>
#include <math.h>

#define BATCH 64
#define HIMG 224
#define WIMG 224
#define IMGPLANE (HIMG*WIMG)   // 50176
#define CF 512
#define HF 28
#define WF 28
#define POS (HF*WF)            // 784
#define ALPHA_C 0.15f
#define EPS_C 1e-6f

#define STRIPS 14              // 16-row strips per sample
#define SROWS 16
#define GROWS 20               // SROWS + 4 halo rows
#define GCOLS 228              // 224 + 2+2 halo cols
#define GSTR 229               // LDS row stride for gray (odd -> 2-way max)
#define VSTR 261               // LDS row stride for var (swizzled cols, max 259)

// ---- ws layout (in floats) ----
#define OFF_HRES 0
#define HRES_CNT (BATCH*HIMG*WF)             // 401,408
#define OFF_BMM (OFF_HRES + HRES_CNT)        // BATCH*STRIPS*2 per-strip [min,max]
#define OFF_AP  (OFF_BMM + BATCH*STRIPS*2)   // 2*BATCH*POS partial channel sums
#define OFF_LP  (OFF_AP + 2*BATCH*POS)       // BATCH per-sample loss partials

// ---- gray -> 5x5 box var (ring-buffer column sums) -> horizontal 16-tap resize ----
__global__ __launch_bounds__(256) void varh_k(const float* __restrict__ img,
                                              float* __restrict__ ws) {
    __shared__ float g[GROWS * GSTR];   // 18,320 B
    __shared__ float v[SROWS * VSTR];   // 16,704 B
    __shared__ float wred[8];
    int b = blockIdx.y, sy = blockIdx.x;
    int tid = threadIdx.x;
    int y0 = sy * SROWS;
    const float* imb = img + (size_t)b * 3 * IMGPLANE;

    // stage gray with 2-halo on all sides (zero-padded)
    for (int i = tid; i < GROWS * GCOLS; i += 256) {
        int gr = i / GCOLS, gc = i - gr * GCOLS;
        int gy = y0 - 2 + gr, gx = gc - 2;
        float u = 0.0f;
        if ((unsigned)gy < HIMG && (unsigned)gx < WIMG) {
            int o = gy * WIMG + gx;
            u = 0.299f * imb[o] + 0.587f * imb[IMGPLANE + o] + 0.114f * imb[2 * IMGPLANE + o];
        }
        g[gr * GSTR + gc] = u;
    }
    // zero var col-halo (4 left jh=0..3, 4 right jh=228..231), 16 rows x 8
    if (tid < SROWS * 8) {
        int r = tid >> 3, p = tid & 7;
        int jh = p + ((p < 4) ? 0 : 224);
        v[r * VSTR + jh + (jh >> 3)] = 0.0f;
    }
    __syncthreads();

    // var: thread (r = tid>>4, 14-col segment s = tid&15)
    int r = tid >> 4, s = tid & 15;
    int x0 = 14 * s;
    const float* gr0 = g + r * GSTR;
    float c1[5], c2[5];
    #pragma unroll
    for (int m = 0; m < 5; m++) {
        float a = 0.0f, a2 = 0.0f;
        #pragma unroll
        for (int k = 0; k < 5; k++) {
            float u = gr0[k * GSTR + x0 + m];
            a += u; a2 += u * u;
        }
        c1[m] = a; c2[m] = a2;
    }
    float vmn = INFINITY, vmx = 0.0f;
    #pragma unroll
    for (int xi = 0; xi < 14; xi++) {
        int p = xi % 5;
        float s1 = c1[p], s2 = c2[p];
        #pragma unroll
        for (int m = 1; m < 5; m++) {
            s1 += c1[(p + m) % 5];
            s2 += c2[(p + m) % 5];
        }
        float m1 = s1 * 0.04f, m2 = s2 * 0.04f;
        float vv = fmaxf(m2 - m1 * m1, 0.0f);
        int jh = x0 + xi + 4;
        v[r * VSTR + jh + (jh >> 3)] = vv;
        vmn = fminf(vmn, vv); vmx = fmaxf(vmx, vv);
        if (xi < 13) {
            float a = 0.0f, a2 = 0.0f;
            #pragma unroll
            for (int k = 0; k < 5; k++) {
                float u = gr0[k * GSTR + x0 + xi + 5];
                a += u; a2 += u * u;
            }
            c1[p] = a; c2[p] = a2;
        }
    }
    // block min/max -> per-strip partial
    #pragma unroll
    for (int o = 32; o > 0; o >>= 1) {
        vmn = fminf(vmn, __shfl_xor(vmn, o));
        vmx = fmaxf(vmx, __shfl_xor(vmx, o));
    }
    int w = tid >> 6;
    if ((tid & 63) == 0) { wred[w] = vmn; wred[4 + w] = vmx; }
    __syncthreads();   // also guards v for h-resize
    if (tid == 0) {
        float mn = fminf(fminf(wred[0], wred[1]), fminf(wred[2], wred[3]));
        float mx = fmaxf(fmaxf(wred[4], wred[5]), fmaxf(wred[6], wred[7]));
        int blk = b * STRIPS + sy;
        ws[OFF_BMM + 2 * blk]     = mn;
        ws[OFF_BMM + 2 * blk + 1] = mx;
    }

    // horizontal 16-tap resize from LDS var; coalesced store of hres strip
    float* hb = ws + OFF_HRES + ((size_t)b * HIMG + y0) * WF;
    for (int idx = tid; idx < SROWS * WF; idx += 256) {   // 448
        int rr = idx / WF, i = idx - rr * WF;
        float acc = 0.0f, wsum = 0.0f;
        int j0 = 8 * i - 4;
        #pragma unroll
        for (int t = 0; t < 16; t++) {
            int j = j0 + t;
            float w_ = 8.0f - fabsf((float)t - 7.5f);
            int jh = j + 4;
            acc += w_ * v[rr * VSTR + jh + (jh >> 3)];   // halo = 0 -> exact
            if ((unsigned)j < WIMG) wsum += w_;
        }
        hb[idx] = acc / wsum;
    }
}

// ---- sum of squares over channels, split in two halves ----
__global__ __launch_bounds__(256) void attn_k(const float* __restrict__ f,
                                              float* __restrict__ ws) {
    int p = blockIdx.x * 256 + threadIdx.x;
    int b = blockIdx.y, z = blockIdx.z;
    if (p >= POS) return;
    const float* fp = f + ((size_t)b * CF + (size_t)z * 256) * POS + p;
    float acc = 0.0f;
    #pragma unroll 16
    for (int c = 0; c < 256; c++) {
        float v = fp[(size_t)c * POS];
        acc += v * v;
    }
    ws[OFF_AP + ((size_t)z * BATCH + b) * POS + p] = acc;
}

// ---- per sample: minmax reduce, vertical 16-tap resize, attn norm, MSE ----
__global__ __launch_bounds__(256) void fused_k(float* __restrict__ ws) {
    __shared__ float hres[HIMG][WF + 1];   // 25,984 B
    __shared__ float wred[4];
    __shared__ float s_mn, s_mx;
    int b = blockIdx.x;
    int tid = threadIdx.x;

    // 1) reduce 14 per-strip var min/max pairs (first wave)
    if (tid < 64) {
        float mn = INFINITY, mx = 0.0f;
        if (tid < STRIPS) {
            mn = ws[OFF_BMM + 2 * (b * STRIPS + tid)];
            mx = ws[OFF_BMM + 2 * (b * STRIPS + tid) + 1];
        }
        #pragma unroll
        for (int o = 8; o > 0; o >>= 1) {
            mn = fminf(mn, __shfl_down(mn, o));
            mx = fmaxf(mx, __shfl_down(mx, o));
        }
        if (tid == 0) { s_mn = mn; s_mx = mx; }
    }

    // 2) stage hres (coalesced)
    const float* hg = ws + OFF_HRES + (size_t)b * HIMG * WF;
    for (int i = tid; i < HIMG * WF; i += 256) {
        int y = i / WF, x = i - y * WF;
        hres[y][x] = hg[i];
    }
    __syncthreads();

    float vmn = s_mn, vmx = s_mx;
    float vden = vmx - vmn;
    bool vok = vden > EPS_C;

    // 3) vertical resize -> sal (regs); attn partials -> attn (regs)
    const float* a0 = ws + OFF_AP + (size_t)b * POS;
    const float* a1 = ws + OFF_AP + ((size_t)BATCH + b) * POS;
    float salv[4], attnv[4];
    float amn = INFINITY, amx = -INFINITY;
    #pragma unroll
    for (int k = 0; k < 4; k++) {
        int idx = tid + 256 * k;
        salv[k] = 0.0f; attnv[k] = 0.0f;
        if (idx < POS) {
            int yo = idx / WF, x = idx - yo * WF;
            float acc = 0.0f, wsum = 0.0f;
            int j0 = 8 * yo - 4;
            #pragma unroll
            for (int t = 0; t < 16; t++) {
                int j = j0 + t;
                float w = 8.0f - fabsf((float)t - 7.5f);
                if ((unsigned)j < HIMG) { acc += w * hres[j][x]; wsum += w; }
            }
            float sraw = acc / wsum;
            salv[k] = vok ? (sraw - vmn) / vden : 0.5f;
            float a = sqrtf((a0[idx] + a1[idx]) * (1.0f / CF));
            attnv[k] = a;
            amn = fminf(amn, a); amx = fmaxf(amx, a);
        }
    }

    // 4) block min/max of attn
    #pragma unroll
    for (int o = 32; o > 0; o >>= 1) {
        amn = fminf(amn, __shfl_xor(amn, o));
        amx = fmaxf(amx, __shfl_xor(amx, o));
    }
    int w = tid >> 6;
    if ((tid & 63) == 0) wred[w] = amn;
    __syncthreads();
    if (tid == 0) s_mn = fminf(fminf(wred[0], wred[1]), fminf(wred[2], wred[3]));
    __syncthreads();
    if ((tid & 63) == 0) wred[w] = amx;
    __syncthreads();
    if (tid == 0) s_mx = fmaxf(fmaxf(wred[0], wred[1]), fmaxf(wred[2], wred[3]));
    __syncthreads();
    amn = s_mn; amx = s_mx;
    float aden = amx - amn;
    bool aok = aden > EPS_C;

    // 5) MSE partial
    float lsum = 0.0f;
    #pragma unroll
    for (int k = 0; k < 4; k++) {
        int idx = tid + 256 * k;
        if (idx < POS) {
            float an = aok ? (attnv[k] - amn) / aden : 0.5f;
            float d = an - salv[k];
            lsum += d * d;
        }
    }
    #pragma unroll
    for (int o = 32; o > 0; o >>= 1) lsum += __shfl_xor(lsum, o);
    if ((tid & 63) == 0) wred[w] = lsum;
    __syncthreads();
    if (tid == 0)
        ws[OFF_LP + b] = wred[0] + wred[1] + wred[2] + wred[3];
}

__global__ void final_k(const float* __restrict__ ws, float* __restrict__ out) {
    int t = threadIdx.x;
    float v = ws[OFF_LP + t];   // one wave
    #pragma unroll
    for (int o = 32; o > 0; o >>= 1) v += __shfl_xor(v, o);
    if (t == 0) out[0] = v * (ALPHA_C / (float)(BATCH * POS));
}

extern "C" void kernel_launch(void* const* d_in, const int* in_sizes, int n_in,
                              void* d_out, int out_size, void* d_ws, size_t ws_size,
                              hipStream_t stream) {
    const float* features = (const float*)d_in[0];  // [64,512,28,28]
    const float* images   = (const float*)d_in[1];  // [64,3,224,224]
    float* ws  = (float*)d_ws;
    float* out = (float*)d_out;

    hipLaunchKernelGGL(varh_k,  dim3(STRIPS, BATCH), dim3(256), 0, stream, images, ws);
    hipLaunchKernelGGL(attn_k,  dim3(4, BATCH, 2),   dim3(256), 0, stream, features, ws);
    hipLaunchKernelGGL(fused_k, dim3(BATCH),         dim3(256), 0, stream, ws);
    hipLaunchKernelGGL(final_k, dim3(1),             dim3(64),  0, stream, ws, out);
}

// Round 4
// 195.686 us; speedup vs baseline: 1.3888x; 1.0028x over previous
//
#include <hip/hip_runtime.h>
#include <math.h>

#define BATCH 64
#define HIMG 224
#define WIMG 224
#define IMGPLANE (HIMG*WIMG)   // 50176
#define CF 512
#define HF 28
#define WF 28
#define POS (HF*WF)            // 784
#define ALPHA_C 0.15f
#define EPS_C 1e-6f

#define STRIPS 14              // 16-row strips per sample
#define SROWS 16
#define GROWS 20               // SROWS + 4 halo rows
#define GCOLS 228              // 224 + 2+2 halo cols
#define GSTR 229               // LDS row stride for gray (odd -> 2-way max)
#define VSTR 261               // LDS row stride for var (swizzled cols)

#define NATTN 512              // attn blocks (4 x 64 x 2)
#define NVARH (STRIPS*BATCH)   // 896

// ---- ws layout (in floats) ----
#define OFF_HRES 0
#define HRES_CNT (BATCH*HIMG*WF)             // 401,408
#define OFF_BMM (OFF_HRES + HRES_CNT)        // BATCH*STRIPS*2 per-strip [min,max]
#define OFF_AP  (OFF_BMM + BATCH*STRIPS*2)   // 2*BATCH*POS partial channel sums
#define OFF_ACC (OFF_AP + 2*BATCH*POS)       // loss accumulator (float)
#define OFF_CNT (OFF_ACC + 1)                // done counter (uint slot)

// ---- fat producer: blocks [0,NATTN) = channel sum-of-squares; rest = gray->var->hres ----
__global__ __launch_bounds__(256) void fat_k(const float* __restrict__ img,
                                             const float* __restrict__ f,
                                             float* __restrict__ ws) {
    __shared__ float g[GROWS * GSTR];   // 18,320 B
    __shared__ float v[SROWS * VSTR];   // 16,704 B
    __shared__ float wred[8];
    int bid = blockIdx.x;
    int tid = threadIdx.x;

    if (bid < NATTN) {
        // -------- attn branch --------
        if (bid == 0 && tid == 0) {
            ws[OFF_ACC] = 0.0f;
            ((unsigned*)ws)[OFF_CNT] = 0u;
        }
        int p = (bid & 3) * 256 + tid;
        int b = (bid >> 2) & 63, z = bid >> 8;
        if (p >= POS) return;
        const float* fp = f + ((size_t)b * CF + (size_t)z * 256) * POS + p;
        float acc = 0.0f;
        #pragma unroll 16
        for (int c = 0; c < 256; c++) {
            float u = fp[(size_t)c * POS];
            acc += u * u;
        }
        ws[OFF_AP + ((size_t)z * BATCH + b) * POS + p] = acc;
        return;
    }

    // -------- varh branch --------
    int vb = bid - NATTN;
    int b = vb / STRIPS, sy = vb - b * STRIPS;
    int y0 = sy * SROWS;
    const float* imb = img + (size_t)b * 3 * IMGPLANE;

    // stage gray with 2-halo on all sides (zero-padded)
    for (int i = tid; i < GROWS * GCOLS; i += 256) {
        int gr = i / GCOLS, gc = i - gr * GCOLS;
        int gy = y0 - 2 + gr, gx = gc - 2;
        float u = 0.0f;
        if ((unsigned)gy < HIMG && (unsigned)gx < WIMG) {
            int o = gy * WIMG + gx;
            u = 0.299f * imb[o] + 0.587f * imb[IMGPLANE + o] + 0.114f * imb[2 * IMGPLANE + o];
        }
        g[gr * GSTR + gc] = u;
    }
    // zero var col-halo (4 left jh=0..3, 4 right jh=228..231)
    if (tid < SROWS * 8) {
        int r = tid >> 3, p = tid & 7;
        int jh = p + ((p < 4) ? 0 : 224);
        v[r * VSTR + jh + (jh >> 3)] = 0.0f;
    }
    __syncthreads();

    // var: thread (r = tid>>4, 14-col segment s = tid&15), ring-buffer column sums
    int r = tid >> 4, s = tid & 15;
    int x0 = 14 * s;
    const float* gr0 = g + r * GSTR;
    float c1[5], c2[5];
    #pragma unroll
    for (int m = 0; m < 5; m++) {
        float a = 0.0f, a2 = 0.0f;
        #pragma unroll
        for (int k = 0; k < 5; k++) {
            float u = gr0[k * GSTR + x0 + m];
            a += u; a2 += u * u;
        }
        c1[m] = a; c2[m] = a2;
    }
    float vmn = INFINITY, vmx = 0.0f;
    #pragma unroll
    for (int xi = 0; xi < 14; xi++) {
        int p = xi % 5;
        float s1 = c1[p], s2 = c2[p];
        #pragma unroll
        for (int m = 1; m < 5; m++) {
            s1 += c1[(p + m) % 5];
            s2 += c2[(p + m) % 5];
        }
        float m1 = s1 * 0.04f, m2 = s2 * 0.04f;
        float vv = fmaxf(m2 - m1 * m1, 0.0f);
        int jh = x0 + xi + 4;
        v[r * VSTR + jh + (jh >> 3)] = vv;
        vmn = fminf(vmn, vv); vmx = fmaxf(vmx, vv);
        if (xi < 13) {
            float a = 0.0f, a2 = 0.0f;
            #pragma unroll
            for (int k = 0; k < 5; k++) {
                float u = gr0[k * GSTR + x0 + xi + 5];
                a += u; a2 += u * u;
            }
            c1[p] = a; c2[p] = a2;
        }
    }
    // block min/max -> per-strip partial
    #pragma unroll
    for (int o = 32; o > 0; o >>= 1) {
        vmn = fminf(vmn, __shfl_xor(vmn, o));
        vmx = fmaxf(vmx, __shfl_xor(vmx, o));
    }
    int w = tid >> 6;
    if ((tid & 63) == 0) { wred[w] = vmn; wred[4 + w] = vmx; }
    __syncthreads();   // also guards v for h-resize
    if (tid == 0) {
        float mn = fminf(fminf(wred[0], wred[1]), fminf(wred[2], wred[3]));
        float mx = fmaxf(fmaxf(wred[4], wred[5]), fmaxf(wred[6], wred[7]));
        int blk = b * STRIPS + sy;
        ws[OFF_BMM + 2 * blk]     = mn;
        ws[OFF_BMM + 2 * blk + 1] = mx;
    }

    // horizontal 16-tap resize from LDS var; coalesced store of hres strip
    float* hb = ws + OFF_HRES + ((size_t)b * HIMG + y0) * WF;
    for (int idx = tid; idx < SROWS * WF; idx += 256) {   // 448
        int rr = idx / WF, i = idx - rr * WF;
        float acc = 0.0f, wsum = 0.0f;
        int j0 = 8 * i - 4;
        #pragma unroll
        for (int t = 0; t < 16; t++) {
            int j = j0 + t;
            float w_ = 8.0f - fabsf((float)t - 7.5f);
            int jh = j + 4;
            acc += w_ * v[rr * VSTR + jh + (jh >> 3)];   // halo = 0 -> exact
            if ((unsigned)j < WIMG) wsum += w_;
        }
        hb[idx] = acc / wsum;
    }
}

// ---- per sample: minmax reduce, vertical 16-tap resize, attn norm, MSE, last-block finish ----
__global__ __launch_bounds__(256) void fused_k(float* __restrict__ ws,
                                               float* __restrict__ out) {
    __shared__ float hres[HIMG][WF + 1];   // 25,984 B
    __shared__ float wred[4];
    __shared__ float s_mn, s_mx;
    int b = blockIdx.x;
    int tid = threadIdx.x;

    // 1) reduce 14 per-strip var min/max pairs (first wave)
    if (tid < 64) {
        float mn = INFINITY, mx = 0.0f;
        if (tid < STRIPS) {
            mn = ws[OFF_BMM + 2 * (b * STRIPS + tid)];
            mx = ws[OFF_BMM + 2 * (b * STRIPS + tid) + 1];
        }
        #pragma unroll
        for (int o = 8; o > 0; o >>= 1) {
            mn = fminf(mn, __shfl_down(mn, o));
            mx = fmaxf(mx, __shfl_down(mx, o));
        }
        if (tid == 0) { s_mn = mn; s_mx = mx; }
    }

    // 2) stage hres (coalesced)
    const float* hg = ws + OFF_HRES + (size_t)b * HIMG * WF;
    for (int i = tid; i < HIMG * WF; i += 256) {
        int y = i / WF, x = i - y * WF;
        hres[y][x] = hg[i];
    }
    __syncthreads();

    float vmn = s_mn, vmx = s_mx;
    float vden = vmx - vmn;
    bool vok = vden > EPS_C;

    // 3) vertical resize -> sal (regs); attn partials -> attn (regs)
    const float* a0 = ws + OFF_AP + (size_t)b * POS;
    const float* a1 = ws + OFF_AP + ((size_t)BATCH + b) * POS;
    float salv[4], attnv[4];
    float amn = INFINITY, amx = -INFINITY;
    #pragma unroll
    for (int k = 0; k < 4; k++) {
        int idx = tid + 256 * k;
        salv[k] = 0.0f; attnv[k] = 0.0f;
        if (idx < POS) {
            int yo = idx / WF, x = idx - yo * WF;
            float acc = 0.0f, wsum = 0.0f;
            int j0 = 8 * yo - 4;
            #pragma unroll
            for (int t = 0; t < 16; t++) {
                int j = j0 + t;
                float w = 8.0f - fabsf((float)t - 7.5f);
                if ((unsigned)j < HIMG) { acc += w * hres[j][x]; wsum += w; }
            }
            float sraw = acc / wsum;
            salv[k] = vok ? (sraw - vmn) / vden : 0.5f;
            float a = sqrtf((a0[idx] + a1[idx]) * (1.0f / CF));
            attnv[k] = a;
            amn = fminf(amn, a); amx = fmaxf(amx, a);
        }
    }

    // 4) block min/max of attn
    #pragma unroll
    for (int o = 32; o > 0; o >>= 1) {
        amn = fminf(amn, __shfl_xor(amn, o));
        amx = fmaxf(amx, __shfl_xor(amx, o));
    }
    int w = tid >> 6;
    if ((tid & 63) == 0) wred[w] = amn;
    __syncthreads();
    if (tid == 0) s_mn = fminf(fminf(wred[0], wred[1]), fminf(wred[2], wred[3]));
    __syncthreads();
    if ((tid & 63) == 0) wred[w] = amx;
    __syncthreads();
    if (tid == 0) s_mx = fmaxf(fmaxf(wred[0], wred[1]), fmaxf(wred[2], wred[3]));
    __syncthreads();
    amn = s_mn; amx = s_mx;
    float aden = amx - amn;
    bool aok = aden > EPS_C;

    // 5) MSE partial
    float lsum = 0.0f;
    #pragma unroll
    for (int k = 0; k < 4; k++) {
        int idx = tid + 256 * k;
        if (idx < POS) {
            float an = aok ? (attnv[k] - amn) / aden : 0.5f;
            float d = an - salv[k];
            lsum += d * d;
        }
    }
    #pragma unroll
    for (int o = 32; o > 0; o >>= 1) lsum += __shfl_xor(lsum, o);
    if ((tid & 63) == 0) wred[w] = lsum;
    __syncthreads();

    // 6) accumulate across blocks; last finished block writes the output
    if (tid == 0) {
        float part = wred[0] + wred[1] + wred[2] + wred[3];
        atomicAdd(ws + OFF_ACC, part);
        __threadfence();
        unsigned old = atomicAdd((unsigned*)ws + OFF_CNT, 1u);
        if (old == BATCH - 1) {
            float tot = atomicAdd(ws + OFF_ACC, 0.0f);  // device-coherent read
            out[0] = tot * (ALPHA_C / (float)(BATCH * POS));
        }
    }
}

extern "C" void kernel_launch(void* const* d_in, const int* in_sizes, int n_in,
                              void* d_out, int out_size, void* d_ws, size_t ws_size,
                              hipStream_t stream) {
    const float* features = (const float*)d_in[0];  // [64,512,28,28]
    const float* images   = (const float*)d_in[1];  // [64,3,224,224]
    float* ws  = (float*)d_ws;
    float* out = (float*)d_out;

    hipLaunchKernelGGL(fat_k,   dim3(NATTN + NVARH), dim3(256), 0, stream,
                       images, features, ws);
    hipLaunchKernelGGL(fused_k, dim3(BATCH),         dim3(256), 0, stream, ws, out);
}

// Round 5
// 191.784 us; speedup vs baseline: 1.4171x; 1.0203x over previous
//
#include <hip/hip_runtime.h>
#include <math.h>

#define BATCH 64
#define HIMG 224
#define WIMG 224
#define IMGPLANE (HIMG*WIMG)   // 50176
#define CF 512
#define HF 28
#define WF 28
#define POS (HF*WF)            // 784
#define ALPHA_C 0.15f
#define EPS_C 1e-6f

#define STRIPS 14              // 16-row strips per sample
#define SROWS 16
#define GROWS 20               // SROWS + 4 halo rows
#define GCOLS 228              // 224 + 2+2 halo cols
#define GSTR 229               // LDS row stride for gray (odd)
#define VSTR 261               // LDS row stride for var (swizzled cols)
#define SHN 4580               // max(GROWS*GSTR=4580, SROWS*VSTR=4176)

#define NATTN 512              // 64 samples x 8 channel-groups
#define NVARH (STRIPS*BATCH)   // 896
// interleave: groups of 11 blocks = 4 attn + 7 varh (1408 = 128*11)

// ---- ws layout (in floats) ----
#define OFF_HRES 0
#define HRES_CNT (BATCH*HIMG*WF)             // 401,408
#define OFF_BMM (OFF_HRES + HRES_CNT)        // BATCH*STRIPS*2 per-strip [min,max]
#define OFF_AP  (OFF_BMM + BATCH*STRIPS*2)   // 8*BATCH*POS partial channel sums
#define OFF_ACC (OFF_AP + 8*BATCH*POS)       // loss accumulator
#define OFF_CNT (OFF_ACC + 1)                // done counter (uint slot)

__global__ __launch_bounds__(256) void fat_k(const float* __restrict__ img,
                                             const float* __restrict__ f,
                                             float* __restrict__ ws) {
    __shared__ float sh[SHN];   // gray, later overlaid with var (18,320 B)
    __shared__ float wred[8];
    int bid = blockIdx.x;
    int tid = threadIdx.x;
    int g11 = bid / 11, r11 = bid - 11 * g11;

    if (r11 < 4) {
        // -------- attn branch: (b, 64-channel group z), float4 over p --------
        int ab = g11 * 4 + r11;
        if (ab == 0 && tid == 0) {
            ws[OFF_ACC] = 0.0f;
            ((unsigned*)ws)[OFF_CNT] = 0u;
        }
        if (tid >= 196) return;     // 196 float4 per plane
        int b = ab >> 3, z = ab & 7;
        const float* fp = f + (size_t)(b * CF + z * 64) * POS + 4 * tid;
        float ax = 0.0f, ay = 0.0f, az = 0.0f, aw = 0.0f;
        #pragma unroll 8
        for (int c = 0; c < 64; c++) {
            float4 u = *(const float4*)(fp + (size_t)c * POS);
            ax += u.x * u.x; ay += u.y * u.y; az += u.z * u.z; aw += u.w * u.w;
        }
        float4 o = make_float4(ax, ay, az, aw);
        *(float4*)(ws + OFF_AP + (size_t)(z * BATCH + b) * POS + 4 * tid) = o;
        return;
    }

    // -------- varh branch --------
    int vb = g11 * 7 + (r11 - 4);
    int b = vb / STRIPS, sy = vb - b * STRIPS;
    int y0 = sy * SROWS;
    const float* imb = img + (size_t)b * 3 * IMGPLANE;

    // stage gray interior via float4 (rows 16B-aligned: 224 floats/row)
    for (int i = tid; i < GROWS * 56; i += 256) {
        int gr = i / 56, q = i - gr * 56;
        int gy = y0 - 2 + gr;
        float gx0 = 0.0f, gx1 = 0.0f, gx2 = 0.0f, gx3 = 0.0f;
        if ((unsigned)gy < HIMG) {
            const float* row = imb + gy * WIMG + 4 * q;
            float4 a = *(const float4*)(row);
            float4 bb = *(const float4*)(row + IMGPLANE);
            float4 c = *(const float4*)(row + 2 * IMGPLANE);
            gx0 = 0.299f * a.x + 0.587f * bb.x + 0.114f * c.x;
            gx1 = 0.299f * a.y + 0.587f * bb.y + 0.114f * c.y;
            gx2 = 0.299f * a.z + 0.587f * bb.z + 0.114f * c.z;
            gx3 = 0.299f * a.w + 0.587f * bb.w + 0.114f * c.w;
        }
        int base = gr * GSTR + 2 + 4 * q;
        sh[base] = gx0; sh[base + 1] = gx1; sh[base + 2] = gx2; sh[base + 3] = gx3;
    }
    // zero gray col-halo (cols 0,1,226,227)
    if (tid < GROWS * 4) {
        int gr = tid >> 2, p = tid & 3;
        int gc = (p < 2) ? p : (224 + p);
        sh[gr * GSTR + gc] = 0.0f;
    }
    __syncthreads();

    // var into registers: thread (r = tid>>4, 14-col segment s = tid&15)
    int r = tid >> 4, s = tid & 15;
    int x0 = 14 * s;
    const float* gr0 = sh + r * GSTR;
    float c1[5], c2[5], vreg[14];
    #pragma unroll
    for (int m = 0; m < 5; m++) {
        float a = 0.0f, a2 = 0.0f;
        #pragma unroll
        for (int k = 0; k < 5; k++) {
            float u = gr0[k * GSTR + x0 + m];
            a += u; a2 += u * u;
        }
        c1[m] = a; c2[m] = a2;
    }
    float vmn = INFINITY, vmx = 0.0f;
    #pragma unroll
    for (int xi = 0; xi < 14; xi++) {
        int p = xi % 5;
        float s1 = c1[p], s2 = c2[p];
        #pragma unroll
        for (int m = 1; m < 5; m++) {
            s1 += c1[(p + m) % 5];
            s2 += c2[(p + m) % 5];
        }
        float m1 = s1 * 0.04f, m2 = s2 * 0.04f;
        float vv = fmaxf(m2 - m1 * m1, 0.0f);
        vreg[xi] = vv;
        vmn = fminf(vmn, vv); vmx = fmaxf(vmx, vv);
        if (xi < 13) {
            float a = 0.0f, a2 = 0.0f;
            #pragma unroll
            for (int k = 0; k < 5; k++) {
                float u = gr0[k * GSTR + x0 + xi + 5];
                a += u; a2 += u * u;
            }
            c1[p] = a; c2[p] = a2;
        }
    }
    #pragma unroll
    for (int o = 32; o > 0; o >>= 1) {
        vmn = fminf(vmn, __shfl_xor(vmn, o));
        vmx = fmaxf(vmx, __shfl_xor(vmx, o));
    }
    __syncthreads();   // all gray reads done -> safe to overlay with var
    int w = tid >> 6;
    if ((tid & 63) == 0) { wred[w] = vmn; wred[4 + w] = vmx; }
    // zero var col-halo (jh 0..3 and 228..231)
    if (tid < SROWS * 8) {
        int rr = tid >> 3, p = tid & 7;
        int jh = p + ((p < 4) ? 0 : 224);
        sh[rr * VSTR + jh + (jh >> 3)] = 0.0f;
    }
    // write var registers into overlaid buffer (swizzled cols)
    #pragma unroll
    for (int xi = 0; xi < 14; xi++) {
        int jh = x0 + xi + 4;
        sh[r * VSTR + jh + (jh >> 3)] = vreg[xi];
    }
    __syncthreads();   // var + wred ready
    if (tid == 0) {
        float mn = fminf(fminf(wred[0], wred[1]), fminf(wred[2], wred[3]));
        float mx = fmaxf(fmaxf(wred[4], wred[5]), fmaxf(wred[6], wred[7]));
        int blk = b * STRIPS + sy;
        ws[OFF_BMM + 2 * blk]     = mn;
        ws[OFF_BMM + 2 * blk + 1] = mx;
    }

    // horizontal 16-tap resize from LDS var; coalesced store of hres strip
    float* hb = ws + OFF_HRES + ((size_t)b * HIMG + y0) * WF;
    for (int idx = tid; idx < SROWS * WF; idx += 256) {   // 448
        int rr = idx / WF, i = idx - rr * WF;
        float acc = 0.0f, wsum = 0.0f;
        int j0 = 8 * i - 4;
        #pragma unroll
        for (int t = 0; t < 16; t++) {
            int j = j0 + t;
            float w_ = 8.0f - fabsf((float)t - 7.5f);
            int jh = j + 4;
            acc += w_ * sh[rr * VSTR + jh + (jh >> 3)];   // halo = 0 -> exact
            if ((unsigned)j < WIMG) wsum += w_;
        }
        hb[idx] = acc / wsum;
    }
}

// ---- per sample: minmax reduce, vertical 16-tap resize, attn norm, MSE, last-block finish ----
__global__ __launch_bounds__(256) void fused_k(float* __restrict__ ws,
                                               float* __restrict__ out) {
    __shared__ float hres[HIMG][WF + 1];   // 25,984 B
    __shared__ float wred[4];
    __shared__ float s_mn, s_mx;
    int b = blockIdx.x;
    int tid = threadIdx.x;

    // 1) reduce 14 per-strip var min/max pairs (first wave)
    if (tid < 64) {
        float mn = INFINITY, mx = 0.0f;
        if (tid < STRIPS) {
            mn = ws[OFF_BMM + 2 * (b * STRIPS + tid)];
            mx = ws[OFF_BMM + 2 * (b * STRIPS + tid) + 1];
        }
        #pragma unroll
        for (int o = 8; o > 0; o >>= 1) {
            mn = fminf(mn, __shfl_down(mn, o));
            mx = fmaxf(mx, __shfl_down(mx, o));
        }
        if (tid == 0) { s_mn = mn; s_mx = mx; }
    }

    // 2) stage hres (coalesced)
    const float* hg = ws + OFF_HRES + (size_t)b * HIMG * WF;
    for (int i = tid; i < HIMG * WF; i += 256) {
        int y = i / WF, x = i - y * WF;
        hres[y][x] = hg[i];
    }
    __syncthreads();

    float vmn = s_mn, vmx = s_mx;
    float vden = vmx - vmn;
    bool vok = vden > EPS_C;

    // 3) vertical resize -> sal (regs); attn from 8 partials (regs)
    const float* ap = ws + OFF_AP + (size_t)b * POS;
    float salv[4], attnv[4];
    float amn = INFINITY, amx = -INFINITY;
    #pragma unroll
    for (int k = 0; k < 4; k++) {
        int idx = tid + 256 * k;
        salv[k] = 0.0f; attnv[k] = 0.0f;
        if (idx < POS) {
            int yo = idx / WF, x = idx - yo * WF;
            float acc = 0.0f, wsum = 0.0f;
            int j0 = 8 * yo - 4;
            #pragma unroll
            for (int t = 0; t < 16; t++) {
                int j = j0 + t;
                float w = 8.0f - fabsf((float)t - 7.5f);
                if ((unsigned)j < HIMG) { acc += w * hres[j][x]; wsum += w; }
            }
            float sraw = acc / wsum;
            salv[k] = vok ? (sraw - vmn) / vden : 0.5f;
            float ssum = 0.0f;
            #pragma unroll
            for (int z = 0; z < 8; z++)
                ssum += ap[(size_t)z * BATCH * POS + idx];
            float a = sqrtf(ssum * (1.0f / CF));
            attnv[k] = a;
            amn = fminf(amn, a); amx = fmaxf(amx, a);
        }
    }

    // 4) block min/max of attn
    #pragma unroll
    for (int o = 32; o > 0; o >>= 1) {
        amn = fminf(amn, __shfl_xor(amn, o));
        amx = fmaxf(amx, __shfl_xor(amx, o));
    }
    int w = tid >> 6;
    if ((tid & 63) == 0) wred[w] = amn;
    __syncthreads();
    if (tid == 0) s_mn = fminf(fminf(wred[0], wred[1]), fminf(wred[2], wred[3]));
    __syncthreads();
    if ((tid & 63) == 0) wred[w] = amx;
    __syncthreads();
    if (tid == 0) s_mx = fmaxf(fmaxf(wred[0], wred[1]), fmaxf(wred[2], wred[3]));
    __syncthreads();
    amn = s_mn; amx = s_mx;
    float aden = amx - amn;
    bool aok = aden > EPS_C;

    // 5) MSE partial
    float lsum = 0.0f;
    #pragma unroll
    for (int k = 0; k < 4; k++) {
        int idx = tid + 256 * k;
        if (idx < POS) {
            float an = aok ? (attnv[k] - amn) / aden : 0.5f;
            float d = an - salv[k];
            lsum += d * d;
        }
    }
    #pragma unroll
    for (int o = 32; o > 0; o >>= 1) lsum += __shfl_xor(lsum, o);
    if ((tid & 63) == 0) wred[w] = lsum;
    __syncthreads();

    // 6) accumulate across blocks; last finished block writes output
    if (tid == 0) {
        float part = wred[0] + wred[1] + wred[2] + wred[3];
        atomicAdd(ws + OFF_ACC, part);
        __threadfence();
        unsigned old = atomicAdd((unsigned*)ws + OFF_CNT, 1u);
        if (old == BATCH - 1) {
            float tot = atomicAdd(ws + OFF_ACC, 0.0f);  // device-coherent read
            out[0] = tot * (ALPHA_C / (float)(BATCH * POS));
        }
    }
}

extern "C" void kernel_launch(void* const* d_in, const int* in_sizes, int n_in,
                              void* d_out, int out_size, void* d_ws, size_t ws_size,
                              hipStream_t stream) {
    const float* features = (const float*)d_in[0];  // [64,512,28,28]
    const float* images   = (const float*)d_in[1];  // [64,3,224,224]
    float* ws  = (float*)d_ws;
    float* out = (float*)d_out;

    hipLaunchKernelGGL(fat_k,   dim3(NATTN + NVARH), dim3(256), 0, stream,
                       images, features, ws);
    hipLaunchKernelGGL(fused_k, dim3(BATCH),         dim3(256), 0, stream, ws, out);
}

// Round 6
// 191.727 us; speedup vs baseline: 1.4175x; 1.0003x over previous
//
#include <hip/hip_runtime.h>
#include <math.h>

#define BATCH 64
#define HIMG 224
#define WIMG 224
#define IMGPLANE (HIMG*WIMG)   // 50176
#define CF 512
#define HF 28
#define WF 28
#define POS (HF*WF)            // 784
#define ALPHA_C 0.15f
#define EPS_C 1e-6f

#define STRIPS 14              // 16-row strips per sample
#define SROWS 16
#define GROWS 20               // SROWS + 4 halo rows
#define GCOLS 228              // 224 + 2+2 halo cols
#define GSTR 229               // LDS row stride for gray (odd)
#define VSTR 261               // LDS row stride for var (swizzled cols)
#define SHN 4580               // max(GROWS*GSTR=4580, SROWS*VSTR=4176)

#define NATTN 512              // 64 samples x 8 channel-groups
#define NVARH (STRIPS*BATCH)   // 896
// interleave: groups of 11 blocks = 4 attn + 7 varh (1408 = 128*11)

// ---- ws layout (in floats) ----
#define OFF_HRES 0
#define HRES_CNT (BATCH*HIMG*WF)             // 401,408
#define OFF_BMM (OFF_HRES + HRES_CNT)        // BATCH*STRIPS*2 per-strip [min,max]
#define OFF_AP  (OFF_BMM + BATCH*STRIPS*2)   // 8*BATCH*POS partial channel sums
#define OFF_ACC (OFF_AP + 8*BATCH*POS)       // loss accumulator
#define OFF_CNT (OFF_ACC + 1)                // done counter (uint slot)

// __launch_bounds__(256,2): 2 waves/EU floor -> ~256 VGPR budget. Round-5's
// implicit allocation gave VGPR_Count=28, strangling memory-level parallelism
// (~1 load in flight). Do NOT tighten this.
__global__ __launch_bounds__(256, 2) void fat_k(const float* __restrict__ img,
                                                const float* __restrict__ f,
                                                float* __restrict__ ws) {
    __shared__ float sh[SHN];   // gray, later overlaid with var (18,320 B)
    __shared__ float wred[8];
    int bid = blockIdx.x;
    int tid = threadIdx.x;
    int g11 = bid / 11, r11 = bid - 11 * g11;

    if (r11 < 4) {
        // -------- attn branch: (b, 64-channel group z), float4 over p --------
        int ab = g11 * 4 + r11;
        if (ab == 0 && tid == 0) {
            ws[OFF_ACC] = 0.0f;
            ((unsigned*)ws)[OFF_CNT] = 0u;
        }
        if (tid >= 196) return;     // 196 float4 per plane
        int b = ab >> 3, z = ab & 7;
        const float* fp = f + (size_t)(b * CF + z * 64) * POS + 4 * tid;
        float ax = 0.0f, ay = 0.0f, az = 0.0f, aw = 0.0f;
        // 16 independent loads staged before consumption -> 16 KB/wave in flight
        #pragma unroll
        for (int cc = 0; cc < 64; cc += 16) {
            float4 u[16];
            #pragma unroll
            for (int j = 0; j < 16; j++)
                u[j] = *(const float4*)(fp + (size_t)(cc + j) * POS);
            #pragma unroll
            for (int j = 0; j < 16; j++) {
                ax += u[j].x * u[j].x; ay += u[j].y * u[j].y;
                az += u[j].z * u[j].z; aw += u[j].w * u[j].w;
            }
        }
        float4 o = make_float4(ax, ay, az, aw);
        *(float4*)(ws + OFF_AP + (size_t)(z * BATCH + b) * POS + 4 * tid) = o;
        return;
    }

    // -------- varh branch --------
    int vb = g11 * 7 + (r11 - 4);
    int b = vb / STRIPS, sy = vb - b * STRIPS;
    int y0 = sy * SROWS;
    const float* imb = img + (size_t)b * 3 * IMGPLANE;

    // stage gray interior via float4 (rows 16B-aligned: 224 floats/row)
    for (int i = tid; i < GROWS * 56; i += 256) {
        int gr = i / 56, q = i - gr * 56;
        int gy = y0 - 2 + gr;
        float gx0 = 0.0f, gx1 = 0.0f, gx2 = 0.0f, gx3 = 0.0f;
        if ((unsigned)gy < HIMG) {
            const float* row = imb + gy * WIMG + 4 * q;
            float4 a = *(const float4*)(row);
            float4 bb = *(const float4*)(row + IMGPLANE);
            float4 c = *(const float4*)(row + 2 * IMGPLANE);
            gx0 = 0.299f * a.x + 0.587f * bb.x + 0.114f * c.x;
            gx1 = 0.299f * a.y + 0.587f * bb.y + 0.114f * c.y;
            gx2 = 0.299f * a.z + 0.587f * bb.z + 0.114f * c.z;
            gx3 = 0.299f * a.w + 0.587f * bb.w + 0.114f * c.w;
        }
        int base = gr * GSTR + 2 + 4 * q;
        sh[base] = gx0; sh[base + 1] = gx1; sh[base + 2] = gx2; sh[base + 3] = gx3;
    }
    // zero gray col-halo (cols 0,1,226,227)
    if (tid < GROWS * 4) {
        int gr = tid >> 2, p = tid & 3;
        int gc = (p < 2) ? p : (224 + p);
        sh[gr * GSTR + gc] = 0.0f;
    }
    __syncthreads();

    // var into registers: thread (r = tid>>4, 14-col segment s = tid&15)
    int r = tid >> 4, s = tid & 15;
    int x0 = 14 * s;
    const float* gr0 = sh + r * GSTR;
    float c1[5], c2[5], vreg[14];
    #pragma unroll
    for (int m = 0; m < 5; m++) {
        float a = 0.0f, a2 = 0.0f;
        #pragma unroll
        for (int k = 0; k < 5; k++) {
            float u = gr0[k * GSTR + x0 + m];
            a += u; a2 += u * u;
        }
        c1[m] = a; c2[m] = a2;
    }
    float vmn = INFINITY, vmx = 0.0f;
    #pragma unroll
    for (int xi = 0; xi < 14; xi++) {
        int p = xi % 5;
        float s1 = c1[p], s2 = c2[p];
        #pragma unroll
        for (int m = 1; m < 5; m++) {
            s1 += c1[(p + m) % 5];
            s2 += c2[(p + m) % 5];
        }
        float m1 = s1 * 0.04f, m2 = s2 * 0.04f;
        float vv = fmaxf(m2 - m1 * m1, 0.0f);
        vreg[xi] = vv;
        vmn = fminf(vmn, vv); vmx = fmaxf(vmx, vv);
        if (xi < 13) {
            float a = 0.0f, a2 = 0.0f;
            #pragma unroll
            for (int k = 0; k < 5; k++) {
                float u = gr0[k * GSTR + x0 + xi + 5];
                a += u; a2 += u * u;
            }
            c1[p] = a; c2[p] = a2;
        }
    }
    #pragma unroll
    for (int o = 32; o > 0; o >>= 1) {
        vmn = fminf(vmn, __shfl_xor(vmn, o));
        vmx = fmaxf(vmx, __shfl_xor(vmx, o));
    }
    __syncthreads();   // all gray reads done -> safe to overlay with var
    int w = tid >> 6;
    if ((tid & 63) == 0) { wred[w] = vmn; wred[4 + w] = vmx; }
    // zero var col-halo (jh 0..3 and 228..231)
    if (tid < SROWS * 8) {
        int rr = tid >> 3, p = tid & 7;
        int jh = p + ((p < 4) ? 0 : 224);
        sh[rr * VSTR + jh + (jh >> 3)] = 0.0f;
    }
    // write var registers into overlaid buffer (swizzled cols)
    #pragma unroll
    for (int xi = 0; xi < 14; xi++) {
        int jh = x0 + xi + 4;
        sh[r * VSTR + jh + (jh >> 3)] = vreg[xi];
    }
    __syncthreads();   // var + wred ready
    if (tid == 0) {
        float mn = fminf(fminf(wred[0], wred[1]), fminf(wred[2], wred[3]));
        float mx = fmaxf(fmaxf(wred[4], wred[5]), fmaxf(wred[6], wred[7]));
        int blk = b * STRIPS + sy;
        ws[OFF_BMM + 2 * blk]     = mn;
        ws[OFF_BMM + 2 * blk + 1] = mx;
    }

    // horizontal 16-tap resize from LDS var; coalesced store of hres strip
    float* hb = ws + OFF_HRES + ((size_t)b * HIMG + y0) * WF;
    for (int idx = tid; idx < SROWS * WF; idx += 256) {   // 448
        int rr = idx / WF, i = idx - rr * WF;
        float acc = 0.0f, wsum = 0.0f;
        int j0 = 8 * i - 4;
        #pragma unroll
        for (int t = 0; t < 16; t++) {
            int j = j0 + t;
            float w_ = 8.0f - fabsf((float)t - 7.5f);
            int jh = j + 4;
            acc += w_ * sh[rr * VSTR + jh + (jh >> 3)];   // halo = 0 -> exact
            if ((unsigned)j < WIMG) wsum += w_;
        }
        hb[idx] = acc / wsum;
    }
}

// ---- per sample: minmax reduce, vertical 16-tap resize, attn norm, MSE, last-block finish ----
__global__ __launch_bounds__(256) void fused_k(float* __restrict__ ws,
                                               float* __restrict__ out) {
    __shared__ float hres[HIMG][WF + 1];   // 25,984 B
    __shared__ float wred[4];
    __shared__ float s_mn, s_mx;
    int b = blockIdx.x;
    int tid = threadIdx.x;

    // 1) reduce 14 per-strip var min/max pairs (first wave)
    if (tid < 64) {
        float mn = INFINITY, mx = 0.0f;
        if (tid < STRIPS) {
            mn = ws[OFF_BMM + 2 * (b * STRIPS + tid)];
            mx = ws[OFF_BMM + 2 * (b * STRIPS + tid) + 1];
        }
        #pragma unroll
        for (int o = 8; o > 0; o >>= 1) {
            mn = fminf(mn, __shfl_down(mn, o));
            mx = fmaxf(mx, __shfl_down(mx, o));
        }
        if (tid == 0) { s_mn = mn; s_mx = mx; }
    }

    // 2) stage hres (coalesced)
    const float* hg = ws + OFF_HRES + (size_t)b * HIMG * WF;
    for (int i = tid; i < HIMG * WF; i += 256) {
        int y = i / WF, x = i - y * WF;
        hres[y][x] = hg[i];
    }
    __syncthreads();

    float vmn = s_mn, vmx = s_mx;
    float vden = vmx - vmn;
    bool vok = vden > EPS_C;

    // 3) vertical resize -> sal (regs); attn from 8 partials (regs)
    const float* ap = ws + OFF_AP + (size_t)b * POS;
    float salv[4], attnv[4];
    float amn = INFINITY, amx = -INFINITY;
    #pragma unroll
    for (int k = 0; k < 4; k++) {
        int idx = tid + 256 * k;
        salv[k] = 0.0f; attnv[k] = 0.0f;
        if (idx < POS) {
            int yo = idx / WF, x = idx - yo * WF;
            float acc = 0.0f, wsum = 0.0f;
            int j0 = 8 * yo - 4;
            #pragma unroll
            for (int t = 0; t < 16; t++) {
                int j = j0 + t;
                float w = 8.0f - fabsf((float)t - 7.5f);
                if ((unsigned)j < HIMG) { acc += w * hres[j][x]; wsum += w; }
            }
            float sraw = acc / wsum;
            salv[k] = vok ? (sraw - vmn) / vden : 0.5f;
            float ssum = 0.0f;
            #pragma unroll
            for (int z = 0; z < 8; z++)
                ssum += ap[(size_t)z * BATCH * POS + idx];
            float a = sqrtf(ssum * (1.0f / CF));
            attnv[k] = a;
            amn = fminf(amn, a); amx = fmaxf(amx, a);
        }
    }

    // 4) block min/max of attn
    #pragma unroll
    for (int o = 32; o > 0; o >>= 1) {
        amn = fminf(amn, __shfl_xor(amn, o));
        amx = fmaxf(amx, __shfl_xor(amx, o));
    }
    int w = tid >> 6;
    if ((tid & 63) == 0) wred[w] = amn;
    __syncthreads();
    if (tid == 0) s_mn = fminf(fminf(wred[0], wred[1]), fminf(wred[2], wred[3]));
    __syncthreads();
    if ((tid & 63) == 0) wred[w] = amx;
    __syncthreads();
    if (tid == 0) s_mx = fmaxf(fmaxf(wred[0], wred[1]), fmaxf(wred[2], wred[3]));
    __syncthreads();
    amn = s_mn; amx = s_mx;
    float aden = amx - amn;
    bool aok = aden > EPS_C;

    // 5) MSE partial
    float lsum = 0.0f;
    #pragma unroll
    for (int k = 0; k < 4; k++) {
        int idx = tid + 256 * k;
        if (idx < POS) {
            float an = aok ? (attnv[k] - amn) / aden : 0.5f;
            float d = an - salv[k];
            lsum += d * d;
        }
    }
    #pragma unroll
    for (int o = 32; o > 0; o >>= 1) lsum += __shfl_xor(lsum, o);
    if ((tid & 63) == 0) wred[w] = lsum;
    __syncthreads();

    // 6) accumulate across blocks; last finished block writes output
    if (tid == 0) {
        float part = wred[0] + wred[1] + wred[2] + wred[3];
        atomicAdd(ws + OFF_ACC, part);
        __threadfence();
        unsigned old = atomicAdd((unsigned*)ws + OFF_CNT, 1u);
        if (old == BATCH - 1) {
            float tot = atomicAdd(ws + OFF_ACC, 0.0f);  // device-coherent read
            out[0] = tot * (ALPHA_C / (float)(BATCH * POS));
        }
    }
}

extern "C" void kernel_launch(void* const* d_in, const int* in_sizes, int n_in,
                              void* d_out, int out_size, void* d_ws, size_t ws_size,
                              hipStream_t stream) {
    const float* features = (const float*)d_in[0];  // [64,512,28,28]
    const float* images   = (const float*)d_in[1];  // [64,3,224,224]
    float* ws  = (float*)d_ws;
    float* out = (float*)d_out;

    hipLaunchKernelGGL(fat_k,   dim3(NATTN + NVARH), dim3(256), 0, stream,
                       images, features, ws);
    hipLaunchKernelGGL(fused_k, dim3(BATCH),         dim3(256), 0, stream, ws, out);
}